// Round 12
// baseline (413.773 us; speedup 1.0000x reference)
//
#include <hip/hip_runtime.h>

typedef __attribute__((ext_vector_type(8))) short short8;
typedef __attribute__((ext_vector_type(4))) float f32x4;
typedef unsigned int uint;

constexpr int Bn    = 16;
constexpr int Cn    = 256;
constexpr int Hn    = 56;
constexpr int Wn    = 56;
constexpr int HWn   = Hn * Wn;       // 3136
constexpr int NPn   = 3200;          // padded N (25 * 128)
constexpr int NHn   = 8;
constexpr int RWn   = 7;
constexpr int NREGn = 49;
constexpr int TOPKn = 4;
// scale folded into stored q: 256^-0.5 * log2(e)  (softmax done in base 2)
constexpr float QKSf = 0.0625f * 1.44269504088896f;

__device__ __forceinline__ float b2f(ushort u) { return __builtin_bit_cast(float, (uint)u << 16); }
__device__ __forceinline__ float b2fl(uint u) { return __builtin_bit_cast(float, u << 16); }
__device__ __forceinline__ float b2fh(uint u) { return __builtin_bit_cast(float, u & 0xffff0000u); }
// packed f32x2 -> bf16x2 (RNE), single HW instruction
__device__ __forceinline__ uint cvtpk(float lo, float hi) {
    uint r;
    asm("v_cvt_pk_bf16_f32 %0, %1, %2" : "=v"(r) : "v"(lo), "v"(hi));
    return r;
}

typedef __attribute__((address_space(3))) uint lds_u32_t;
typedef __attribute__((address_space(1))) const uint glb_u32_t;
__device__ __forceinline__ void gl_lds16(const ushort* g, ushort* l) {
    __builtin_amdgcn_global_load_lds((glb_u32_t*)g, (lds_u32_t*)l, 16, 0, 0);
}

// ---------------------------------------------------------------------------
// convert qkv_w (768x256) and out_w (256x256) f32 -> bf16
// ---------------------------------------------------------------------------
__global__ __launch_bounds__(256)
void convert_w(const float* __restrict__ qw, const float* __restrict__ ow,
               ushort* __restrict__ wq, ushort* __restrict__ wo)
{
    const int e = (blockIdx.x * 256 + threadIdx.x) * 4;   // 262144 total
    if (e < 196608) {
        const float4 v = *(const float4*)(qw + e);
        uint2 w; w.x = cvtpk(v.x, v.y); w.y = cvtpk(v.z, v.w);
        *(uint2*)(wq + e) = w;
    } else {
        const int e2 = e - 196608;
        const float4 v = *(const float4*)(ow + e2);
        uint2 w; w.x = cvtpk(v.x, v.y); w.y = cvtpk(v.z, v.w);
        *(uint2*)(wo + e2) = w;
    }
}

// ---------------------------------------------------------------------------
// x (B,256,3136) f32 -> XT (B,3200,256) bf16 (transposed, N-major), FUSED
// with region-pool partial sums (deterministic, no atomics).
// ---------------------------------------------------------------------------
__global__ __launch_bounds__(256)
void convert_x(const float* __restrict__ x, ushort* __restrict__ xt,
               float* __restrict__ part)
{
    __shared__ float tile[64][65];
    const int p0 = blockIdx.x * 64, c0 = blockIdx.y * 64, b = blockIdx.z;
    const int tid = threadIdx.x;
    #pragma unroll
    for (int it = 0; it < 4; ++it) {
        const int slot = it * 256 + tid;
        const int c = slot >> 4, p4 = (slot & 15) << 2;
        const float4 v = *(const float4*)(x + ((size_t)b * Cn + c0 + c) * HWn + p0 + p4);
        tile[c][p4 + 0] = v.x; tile[c][p4 + 1] = v.y;
        tile[c][p4 + 2] = v.z; tile[c][p4 + 3] = v.w;
    }
    __syncthreads();
    #pragma unroll
    for (int it = 0; it < 4; ++it) {
        const int slot = it * 256 + tid;
        const int p = slot >> 4, c4 = (slot & 15) << 2;
        uint2 w;
        w.x = cvtpk(tile[c4 + 0][p], tile[c4 + 1][p]);
        w.y = cvtpk(tile[c4 + 2][p], tile[c4 + 3][p]);
        *(uint2*)(xt + ((size_t)b * NPn + p0 + p) * Cn + c0 + c4) = w;
    }
    // pooling partials: two 8-pixel run sums per thread
    {
        const int c = tid >> 2, q = tid & 3;
        float sA = 0.f, sB = 0.f;
        #pragma unroll
        for (int p = 0; p < 8; ++p) sA += tile[c][q * 16 + p];
        #pragma unroll
        for (int p = 0; p < 8; ++p) sB += tile[c][q * 16 + 8 + p];
        float* pp = part + ((((size_t)b * 4 + blockIdx.y) * 49 + blockIdx.x) * 64 + c) * 8 + q * 2;
        *(float2*)pp = make_float2(sA, sB);
    }
}

// ---------------------------------------------------------------------------
// reduce partials -> xr (B,256,49) f32 region means.
// ---------------------------------------------------------------------------
__global__ __launch_bounds__(256)
void reduce_pool(const float* __restrict__ part, float* __restrict__ xr)
{
    const int gid = blockIdx.x * 256 + threadIdx.x;   // 200704 = 784*256
    const int r = gid % NREGn;
    const int t = gid / NREGn;
    const int c = t % Cn, b = t / Cn;
    const int ry = r / 7, rx = r % 7;
    const float* pb = part + ((((size_t)b * 4 + (c >> 6)) * 49 + 7 * ry) * 64 + (c & 63)) * 8;
    float s = 0.f;
    #pragma unroll
    for (int j = 0; j < 7; ++j) {
        const int s0 = (rx - j + 7) % 7;
        s += pb[j * 512 + s0];
        if (s0 == 0) s += pb[j * 512 + 7];
    }
    xr[gid] = s * (1.0f / 64.0f);
}

// ---------------------------------------------------------------------------
// pooled q_r/k_r in f32 from pooled x: one output per thread
// ---------------------------------------------------------------------------
__global__ __launch_bounds__(256)
void qkr_gemm(const float* __restrict__ qw, const float* __restrict__ qb,
              const float* __restrict__ xr, float* __restrict__ qr,
              float* __restrict__ kr)
{
    const int gid = blockIdx.x * 256 + threadIdx.x;    // 401,408 = 16*512*49
    const int j = gid % NREGn;
    const int t = gid / NREGn;
    const int m = t & 511;
    const int b = t >> 9;
    const float* wr = qw + (size_t)m * Cn;
    const float* xb = xr + (size_t)b * Cn * NREGn + j;
    float s = 0.f;
    #pragma unroll 8
    for (int c = 0; c < Cn; ++c)
        s = fmaf(wr[c], xb[c * NREGn], s);
    s += qb[m];
    if (m < Cn) qr[((size_t)b * Cn + m) * NREGn + j] = s;
    else        kr[((size_t)b * Cn + (m - Cn)) * NREGn + j] = s;
}

// ---------------------------------------------------------------------------
// routing: a[i][j] = sum_c qr[b,c,i]*kr[b,c,j]; top-4 per row. grid (7,16)
// ---------------------------------------------------------------------------
__global__ __launch_bounds__(256)
void routing(const float* __restrict__ qr, const float* __restrict__ kr,
             int* __restrict__ idxo)
{
    const int ig = blockIdx.x, b = blockIdx.y;
    __shared__ float ksh[Cn][NREGn];        // 50 KB
    __shared__ float qsh[Cn][7];
    __shared__ float ar[7][NREGn];
    const float* qb = qr + (size_t)b * Cn * NREGn;
    const float* kb = kr + (size_t)b * Cn * NREGn;
    for (int e = threadIdx.x; e < Cn * NREGn; e += 256)
        ksh[e / NREGn][e % NREGn] = kb[e];             // coalesced stage
    for (int e = threadIdx.x; e < Cn * 7; e += 256)
        qsh[e / 7][e % 7] = qb[(e / 7) * NREGn + ig * 7 + (e % 7)];
    __syncthreads();
    for (int e = threadIdx.x; e < 7 * NREGn; e += 256) {
        const int il = e / NREGn, j = e % NREGn;
        float s = 0.f;
        for (int c = 0; c < Cn; ++c)
            s = fmaf(qsh[c][il], ksh[c][j], s);
        ar[il][j] = s;
    }
    __syncthreads();
    if (threadIdx.x < 7) {
        const int il = threadIdx.x;
        float bv0 = -3.0e38f, bv1 = -3.0e38f, bv2 = -3.0e38f, bv3 = -3.0e38f;
        int bi0 = 0, bi1 = 0, bi2 = 0, bi3 = 0;
        for (int j = 0; j < NREGn; ++j) {
            const float v = ar[il][j];
            if (v > bv3) {
                if (v > bv0)      { bv3=bv2; bi3=bi2; bv2=bv1; bi2=bi1; bv1=bv0; bi1=bi0; bv0=v; bi0=j; }
                else if (v > bv1) { bv3=bv2; bi3=bi2; bv2=bv1; bi2=bi1; bv1=v; bi1=j; }
                else if (v > bv2) { bv3=bv2; bi3=bi2; bv2=v; bi2=j; }
                else              { bv3=v; bi3=j; }
            }
        }
        int* o = idxo + ((size_t)b * NREGn + ig * 7 + il) * TOPKn;
        o[0] = bi0; o[1] = bi1; o[2] = bi2; o[3] = bi3;
    }
}

// ---------------------------------------------------------------------------
// bf16 MFMA GEMM, 128x128 tile, 4 waves, 2-phase double-buffered staging.
// XCD-swizzled grid. MODE 0: qkv -> q(scaled)/k seq + v -> VT.
// MODE 1: out proj -> f32 plane.
// ---------------------------------------------------------------------------
template<int MODE>
__global__ __launch_bounds__(256)
void gemm_mfma(const ushort* __restrict__ Wb, const float* __restrict__ bias,
               const ushort* __restrict__ Bt,
               ushort* __restrict__ oq, ushort* __restrict__ ok,
               ushort* __restrict__ ovt, float* __restrict__ of)
{
    constexpr int K = Cn;
    int bb, bx, by;
    {
        const int flat = blockIdx.x;
        if (MODE == 0) {                       // 2400 = 8*300 blocks
            const int sw = (flat & 7) * 300 + (flat >> 3);
            bb = sw / 150; const int r2 = sw % 150; bx = r2 / 6; by = r2 % 6;
        } else {                               // 800 = 8*100 blocks
            const int sw = (flat & 7) * 100 + (flat >> 3);
            bb = sw / 50;  const int r2 = sw % 50;  bx = r2 / 2; by = r2 % 2;
        }
    }
    const int n0 = bx * 128;
    const int m0 = by * 128;
    __shared__ ushort As[2][4096];
    __shared__ ushort Bs[2][4096];
    const int tid = threadIdx.x;
    const int wid = tid >> 6, lane = tid & 63;
    const int wm = wid >> 1, wn = wid & 1;
    const ushort* Bb = Bt + (size_t)bb * NPn * K;

    f32x4 acc[4][4];
    #pragma unroll
    for (int i = 0; i < 4; ++i)
        #pragma unroll
        for (int j = 0; j < 4; ++j)
            acc[i][j] = (f32x4){0.f, 0.f, 0.f, 0.f};

    const int cA = wid * 64 + lane;
    const int rowA = cA >> 2, koffA = (cA & 3) << 3;

    const ushort* wA0 = Wb + (size_t)(m0 + rowA) * K + koffA;
    const ushort* wA1 = Wb + (size_t)(m0 + rowA + 64) * K + koffA;
    const ushort* bB0 = Bb + (size_t)(n0 + rowA) * K + koffA;
    const ushort* bB1 = Bb + (size_t)(n0 + rowA + 64) * K + koffA;

#define STAGE(buf, k0)                                              \
    do {                                                            \
        gl_lds16(wA0 + (k0), &As[buf][wid * 512]);                  \
        gl_lds16(wA1 + (k0), &As[buf][2048 + wid * 512]);           \
        gl_lds16(bB0 + (k0), &Bs[buf][wid * 512]);                  \
        gl_lds16(bB1 + (k0), &Bs[buf][2048 + wid * 512]);           \
    } while (0)

    STAGE(0, 0);
    __syncthreads();
    int cur = 0;
    for (int k0 = 0; k0 < K; k0 += 32, cur ^= 1) {
        if (k0 + 32 < K) STAGE(cur ^ 1, k0 + 32);
        short8 a[4], b[4];
        #pragma unroll
        for (int i = 0; i < 4; ++i)
            a[i] = *(const short8*)(&As[cur][(wm * 64 + i * 16 + (lane & 15)) * 32 + ((lane >> 4) << 3)]);
        #pragma unroll
        for (int j = 0; j < 4; ++j)
            b[j] = *(const short8*)(&Bs[cur][(wn * 64 + j * 16 + (lane & 15)) * 32 + ((lane >> 4) << 3)]);
        #pragma unroll
        for (int i = 0; i < 4; ++i)
            #pragma unroll
            for (int j = 0; j < 4; ++j)
                acc[i][j] = __builtin_amdgcn_mfma_f32_16x16x32_bf16(a[i], b[j], acc[i][j], 0, 0, 0);
        __syncthreads();   // drains vmcnt (next-tile stage) + lgkm (our reads)
    }
#undef STAGE

    if (MODE == 0) {
        #pragma unroll
        for (int i = 0; i < 4; ++i) {
            const int m_base = m0 + wm * 64 + i * 16;
            const int which = m_base >> 8;                       // 0=q 1=k 2=v
            const int hh = (m_base >> 5) & 7;
            const int db = (m_base & 31) + ((lane >> 4) << 2);   // 0..28
            const float4 b4 = *(const float4*)(bias + m_base + ((lane >> 4) << 2));
            #pragma unroll
            for (int j = 0; j < 4; ++j) {
                const int n = n0 + wn * 64 + j * 16 + (lane & 15);
                if (n < HWn) {
                    const int py = n / 56, px = n % 56;
                    const int rr = (py >> 3) * 7 + (px >> 3);
                    const int ss = ((py & 7) << 3) + (px & 7);
                    if (which == 0) {
                        uint2 w;
                        w.x = cvtpk((acc[i][j][0] + b4.x) * QKSf, (acc[i][j][1] + b4.y) * QKSf);
                        w.y = cvtpk((acc[i][j][2] + b4.z) * QKSf, (acc[i][j][3] + b4.w) * QKSf);
                        *(uint2*)(oq + (((size_t)bb * NHn + hh) * HWn + rr * 64 + ss) * 32 + db) = w;
                    } else if (which == 1) {
                        uint2 w;
                        w.x = cvtpk(acc[i][j][0] + b4.x, acc[i][j][1] + b4.y);
                        w.y = cvtpk(acc[i][j][2] + b4.z, acc[i][j][3] + b4.w);
                        *(uint2*)(ok + (((size_t)bb * NHn + hh) * HWn + rr * 64 + ss) * 32 + db) = w;
                    } else {
                        const size_t vtb = ((size_t)(bb * NHn + hh) * 32 + db) * HWn + rr * 64 + ss;
                        const uint lo = cvtpk(acc[i][j][0] + b4.x, acc[i][j][1] + b4.y);
                        const uint hi = cvtpk(acc[i][j][2] + b4.z, acc[i][j][3] + b4.w);
                        ovt[vtb + 0 * HWn] = (ushort)lo;
                        ovt[vtb + 1 * HWn] = (ushort)(lo >> 16);
                        ovt[vtb + 2 * HWn] = (ushort)hi;
                        ovt[vtb + 3 * HWn] = (ushort)(hi >> 16);
                    }
                }
            }
        }
    } else {
        #pragma unroll
        for (int i = 0; i < 4; ++i) {
            const int mb = m0 + wm * 64 + i * 16 + ((lane >> 4) << 2);
            const float4 b4 = *(const float4*)(bias + mb);
            #pragma unroll
            for (int j = 0; j < 4; ++j) {
                const int n = n0 + wn * 64 + j * 16 + (lane & 15);
                if (n < HWn) {
                    const int rr = n >> 6, ss = n & 63;
                    const int py = (rr / 7) * 8 + (ss >> 3);
                    const int px = (rr % 7) * 8 + (ss & 7);
                    float* od = of + ((size_t)bb * Cn + mb) * HWn + py * 56 + px;
                    od[0 * HWn] = acc[i][j][0] + b4.x;
                    od[1 * HWn] = acc[i][j][1] + b4.y;
                    od[2 * HWn] = acc[i][j][2] + b4.z;
                    od[3 * HWn] = acc[i][j][3] + b4.w;
                }
            }
        }
    }
}

// ---------------------------------------------------------------------------
// LePE: depthwise 5x5 SAME conv, 8-wide strip per thread, region-ordered I/O.
// ---------------------------------------------------------------------------
__global__ __launch_bounds__(256)
void lepe(const ushort* __restrict__ vt, const float* __restrict__ lw,
          const float* __restrict__ lb, ushort* __restrict__ lbuf)
{
    const int gid = blockIdx.x * 256 + threadIdx.x;   // 1,605,632 = 6272*256
    const int plane = gid / 392;                      // b*256 + c
    const int within = gid - plane * 392;
    const int row = within / 7;                       // 0..55
    const int sx  = within - row * 7;                 // 0..6
    const int px0 = sx * 8;
    const int c = plane & 255;
    const ushort* vp = vt + (size_t)plane * HWn;
    const float* wc = lw + c * 25;

    float wreg[25];
    #pragma unroll
    for (int i = 0; i < 25; ++i) wreg[i] = wc[i];

    float acc[8];
    const float bias = lb[c];
    #pragma unroll
    for (int j = 0; j < 8; ++j) acc[j] = bias;

    #pragma unroll
    for (int kh = 0; kh < 5; ++kh) {
        const int iy = row + kh - 2;
        if (iy < 0 || iy >= Hn) continue;
        const int ry = iy >> 3, il = iy & 7;
        const ushort* rp = vp + (ry * 7 + sx) * 64 + il * 8;
        const uint  a = *(const uint*)(rp - 64 + 6);
        const uint4 M = *(const uint4*)(rp);
        const uint  e = *(const uint*)(rp + 64);
        float w[12];
        w[0]  = (px0 >= 2)      ? b2fl(a)   : 0.f;
        w[1]  = (px0 >= 1)      ? b2fh(a)   : 0.f;
        w[2]  = b2fl(M.x); w[3]  = b2fh(M.x);
        w[4]  = b2fl(M.y); w[5]  = b2fh(M.y);
        w[6]  = b2fl(M.z); w[7]  = b2fh(M.z);
        w[8]  = b2fl(M.w); w[9]  = b2fh(M.w);
        w[10] = (px0 + 8 < Wn)  ? b2fl(e)   : 0.f;
        w[11] = (px0 + 9 < Wn)  ? b2fh(e)   : 0.f;
        #pragma unroll
        for (int kw = 0; kw < 5; ++kw) {
            const float ww = wreg[kh * 5 + kw];
            #pragma unroll
            for (int j = 0; j < 8; ++j)
                acc[j] = fmaf(w[j + kw], ww, acc[j]);
        }
    }
    ushort* op = lbuf + (size_t)plane * HWn + ((row >> 3) * 7 + sx) * 64 + (row & 7) * 8;
    uint2 wa, wb;
    wa.x = cvtpk(acc[0], acc[1]); wa.y = cvtpk(acc[2], acc[3]);
    wb.x = cvtpk(acc[4], acc[5]); wb.y = cvtpk(acc[6], acc[7]);
    *(uint2*)(op)     = wa;
    *(uint2*)(op + 4) = wb;
}

// ---------------------------------------------------------------------------
// MFMA attention: r6 dataflow (combined K+V prefetch, defer-max branch kept
// for regalloc) with hot-path shuffle chains removed: (a) in-lane partial
// denominator (rescaled by corr on rare defer-max events), reduced once per
// qt at the end; (b) steady-state defer check uses lane-local max in __all
// (equivalent to reducing first); max-reduce shuffles moved inside the rare
// branch. 1-wave blocks (64 thr, 8KB LDS) for 4 waves/SIMD occupancy.
// ---------------------------------------------------------------------------
__global__ __launch_bounds__(64, 4)
void attention3(const ushort* __restrict__ qs, const ushort* __restrict__ ks,
                const ushort* __restrict__ vt, const int* __restrict__ idxp,
                const ushort* __restrict__ lep, ushort* __restrict__ yt)
{
    const int flat = blockIdx.x;                  // 6272 = 8*784
    const int sw = (flat & 7) * 784 + (flat >> 3);
    const int b = sw / 392;
    const int rem = sw % 392;
    const int h = rem / 49;
    const int r = rem % 49;
    const int lane = threadIdx.x;
    const int col = lane & 15, g = lane >> 4;
    __shared__ ushort pw[4096];                   // 8KB, one wave per block

    const size_t hb = ((size_t)b * NHn + h) * HWn;
    const size_t vtb = (size_t)(b * NHn + h) * 32;

    short8 qf[4];
    #pragma unroll
    for (int qt = 0; qt < 4; ++qt)
        qf[qt] = *(const short8*)(qs + (hb + (size_t)r * 64 + qt * 16 + col) * 32 + g * 8);

    f32x4 o[4][2];
    #pragma unroll
    for (int qt = 0; qt < 4; ++qt) {
        o[qt][0] = (f32x4){0.f, 0.f, 0.f, 0.f};
        o[qt][1] = (f32x4){0.f, 0.f, 0.f, 0.f};
    }
    float mrow[4] = {-3.0e38f, -3.0e38f, -3.0e38f, -3.0e38f};
    float psum[4] = {0.f, 0.f, 0.f, 0.f};   // in-lane partial denominator

    const int* ip = idxp + ((size_t)b * NREGn + r) * TOPKn;
    const int4 i4 = *(const int4*)ip;
    const int idxs[4] = {i4.x, i4.y, i4.z, i4.w};

    short8 kfA[4], vfA[4];   // vf[dt*2+kc]
    {
        const int rr = idxs[0];
        #pragma unroll
        for (int kt = 0; kt < 4; ++kt)
            kfA[kt] = *(const short8*)(ks + (hb + (size_t)rr * 64 + kt * 16 + col) * 32 + g * 8);
        #pragma unroll
        for (int dt = 0; dt < 2; ++dt)
            #pragma unroll
            for (int kc = 0; kc < 2; ++kc)
                vfA[dt * 2 + kc] = *(const short8*)(vt + (vtb + dt * 16 + col) * HWn
                                                    + (size_t)rr * 64 + kc * 32 + g * 8);
    }

    #pragma unroll
    for (int t = 0; t < TOPKn; ++t) {
        short8 kfB[4], vfB[4];
        if (t < 3) {   // prefetch next region while computing this one
            const int rr = idxs[t + 1];
            #pragma unroll
            for (int kt = 0; kt < 4; ++kt)
                kfB[kt] = *(const short8*)(ks + (hb + (size_t)rr * 64 + kt * 16 + col) * 32 + g * 8);
            #pragma unroll
            for (int dt = 0; dt < 2; ++dt)
                #pragma unroll
                for (int kc = 0; kc < 2; ++kc)
                    vfB[dt * 2 + kc] = *(const short8*)(vt + (vtb + dt * 16 + col) * HWn
                                                         + (size_t)rr * 64 + kc * 32 + g * 8);
        }

        #pragma unroll
        for (int qt = 0; qt < 4; ++qt) {
            f32x4 s[4];
            #pragma unroll
            for (int kt = 0; kt < 4; ++kt)
                s[kt] = __builtin_amdgcn_mfma_f32_16x16x32_bf16(
                    kfA[kt], qf[qt], (f32x4){0.f, 0.f, 0.f, 0.f}, 0, 0, 0);

            // lane-local max (no cross-lane reduce in steady state)
            float mx = s[0][0];
            #pragma unroll
            for (int kt = 0; kt < 4; ++kt)
                #pragma unroll
                for (int e = 0; e < 4; ++e)
                    mx = fmaxf(mx, s[kt][e]);
            // defer-max: rescale only when some lane's local max grew by > 8
            if (!__all(mx - mrow[qt] <= 8.f)) {
                float mr = mx;
                mr = fmaxf(mr, __shfl_xor(mr, 16));
                mr = fmaxf(mr, __shfl_xor(mr, 32));
                const float mnew = fmaxf(mrow[qt], mr);
                const float corr = exp2f(mrow[qt] - mnew);
                mrow[qt] = mnew;
                psum[qt] *= corr;
                #pragma unroll
                for (int reg = 0; reg < 4; ++reg) {
                    const float cr = __shfl(corr, g * 4 + reg);
                    o[qt][0][reg] *= cr;
                    o[qt][1][reg] *= cr;
                }
            }
            float ls = 0.f;
            #pragma unroll
            for (int kt = 0; kt < 4; ++kt)
                #pragma unroll
                for (int e = 0; e < 4; ++e) {
                    const float p = exp2f(s[kt][e] - mrow[qt]);
                    s[kt][e] = p; ls += p;
                }
            psum[qt] += ls;
            const int qrow = qt * 16 + col;
            const int swz = (qrow & 7) << 4;
            #pragma unroll
            for (int kt = 0; kt < 4; ++kt) {
                uint2 pk;
                pk.x = cvtpk(s[kt][0], s[kt][1]);
                pk.y = cvtpk(s[kt][2], s[kt][3]);
                const int byt = (qrow * 128 + kt * 32 + g * 8) ^ swz;
                *(uint2*)((char*)pw + byt) = pk;
            }
        }

        #pragma unroll
        for (int kc = 0; kc < 2; ++kc)
            #pragma unroll
            for (int qt = 0; qt < 4; ++qt) {
                const int qrow = qt * 16 + col;
                const int byt = (qrow * 128 + kc * 64 + g * 16) ^ ((qrow & 7) << 4);
                const short8 pf = *(const short8*)((const char*)pw + byt);
                o[qt][0] = __builtin_amdgcn_mfma_f32_16x16x32_bf16(pf, vfA[0 * 2 + kc], o[qt][0], 0, 0, 0);
                o[qt][1] = __builtin_amdgcn_mfma_f32_16x16x32_bf16(pf, vfA[1 * 2 + kc], o[qt][1], 0, 0, 0);
            }

        if (t < 3) {
            #pragma unroll
            for (int i = 0; i < 4; ++i) { kfA[i] = kfB[i]; vfA[i] = vfB[i]; }
        }
    }

    // denominator: one cross-lane reduction per qt, then normalize + bounce O
    #pragma unroll
    for (int qt = 0; qt < 4; ++qt) {
        float ps = psum[qt];
        ps += __shfl_xor(ps, 16);
        ps += __shfl_xor(ps, 32);
        const float linv = 1.0f / ps;
        #pragma unroll
        for (int reg = 0; reg < 4; ++reg) {
            const float li = __shfl(linv, g * 4 + reg);
            const int row = qt * 16 + g * 4 + reg;
            const int swz = ((row >> 1) & 3) << 4;
            const uint pk = cvtpk(o[qt][0][reg] * li, o[qt][1][reg] * li);
            const int byt0 = (row * 64 + col * 2) ^ swz;
            const int byt1 = (row * 64 + (16 + col) * 2) ^ swz;
            *(ushort*)((char*)pw + byt0) = (ushort)pk;
            *(ushort*)((char*)pw + byt1) = (ushort)(pk >> 16);
        }
    }
    const ushort* lp = lep + ((size_t)b * Cn + h * 32) * HWn + (size_t)r * 64 + lane;
    ushort* yp = yt + ((size_t)b * NPn + (size_t)r * 64 + lane) * Cn + h * 32;
    const int swl = ((lane >> 1) & 3) << 4;
    #pragma unroll
    for (int c4 = 0; c4 < 8; ++c4) {
        const int byt = (lane * 64 + c4 * 8) ^ swl;
        const ushort4 ov = *(const ushort4*)((const char*)pw + byt);
        const float a0 = b2f(ov.x) + b2f(lp[(size_t)(c4 * 4 + 0) * HWn]);
        const float a1 = b2f(ov.y) + b2f(lp[(size_t)(c4 * 4 + 1) * HWn]);
        const float a2 = b2f(ov.z) + b2f(lp[(size_t)(c4 * 4 + 2) * HWn]);
        const float a3 = b2f(ov.w) + b2f(lp[(size_t)(c4 * 4 + 3) * HWn]);
        uint2 w4; w4.x = cvtpk(a0, a1); w4.y = cvtpk(a2, a3);
        *(uint2*)(yp + c4 * 4) = w4;
    }
}

// ---------------------------------------------------------------------------
extern "C" void kernel_launch(void* const* d_in, const int* in_sizes, int n_in,
                              void* d_out, int out_size, void* d_ws, size_t ws_size,
                              hipStream_t stream)
{
    const float* x      = (const float*)d_in[0];
    const float* qkv_w  = (const float*)d_in[1];
    const float* qkv_b  = (const float*)d_in[2];
    const float* lepe_w = (const float*)d_in[3];
    const float* lepe_b = (const float*)d_in[4];
    const float* out_w  = (const float*)d_in[5];
    const float* out_b  = (const float*)d_in[6];
    float* out = (float*)d_out;

    char* ws = (char*)d_ws;
    ushort* XT = (ushort*)(ws);                                  // 26,214,400
    ushort* YT = (ushort*)(ws + 26214400);                       // 26,214,400
    ushort* QS = (ushort*)(ws + 52428800);                       // 25,690,112
    ushort* KS = (ushort*)(ws + 78118912);                       // 25,690,112
    ushort* VT = (ushort*)(ws + 103809024);                      // 25,690,112
    ushort* LB = (ushort*)(ws + 129499136);                      // 25,690,112
    ushort* WQ = (ushort*)(ws + 155189248);                      // 393,216
    ushort* WO = (ushort*)(ws + 155582464);                      // 131,072
    float*  XR = (float*)(ws + 155713536);                       // 802,816
    float*  QR = (float*)(ws + 156516352);                       // 802,816
    float*  KR = (float*)(ws + 157319168);                       // 802,816
    int*   IDX = (int*)(ws + 158121984);                         // 12,544
    float* PART = (float*)(ws + 158134528);                      // 6,422,528

    convert_w<<<256, 256, 0, stream>>>(qkv_w, out_w, WQ, WO);
    convert_x<<<dim3(49, 4, 16), 256, 0, stream>>>(x, XT, PART);
    reduce_pool<<<784, 256, 0, stream>>>(PART, XR);
    qkr_gemm<<<1568, 256, 0, stream>>>(qkv_w, qkv_b, XR, QR, KR);
    routing<<<dim3(7, 16), 256, 0, stream>>>(QR, KR, IDX);
    gemm_mfma<0><<<2400, 256, 0, stream>>>(WQ, qkv_b, XT, QS, KS, VT, nullptr);
    lepe<<<6272, 256, 0, stream>>>(VT, lepe_w, lepe_b, LB);
    attention3<<<6272, 64, 0, stream>>>(QS, KS, VT, IDX, LB, YT);
    gemm_mfma<1><<<800, 256, 0, stream>>>(WO, out_b, YT, nullptr, nullptr, nullptr, out);
}

// Round 13
// 243.276 us; speedup vs baseline: 1.7008x; 1.7008x over previous
//
#include <hip/hip_runtime.h>

typedef __attribute__((ext_vector_type(8))) short short8;
typedef __attribute__((ext_vector_type(4))) float f32x4;
typedef unsigned int uint;

constexpr int Bn    = 16;
constexpr int Cn    = 256;
constexpr int Hn    = 56;
constexpr int Wn    = 56;
constexpr int HWn   = Hn * Wn;       // 3136
constexpr int NPn   = 3200;          // padded N (25 * 128)
constexpr int NHn   = 8;
constexpr int RWn   = 7;
constexpr int NREGn = 49;
constexpr int TOPKn = 4;
// scale folded into stored q: 256^-0.5 * log2(e)  (softmax done in base 2)
constexpr float QKSf = 0.0625f * 1.44269504088896f;

__device__ __forceinline__ float b2f(ushort u) { return __builtin_bit_cast(float, (uint)u << 16); }
__device__ __forceinline__ float b2fl(uint u) { return __builtin_bit_cast(float, u << 16); }
__device__ __forceinline__ float b2fh(uint u) { return __builtin_bit_cast(float, u & 0xffff0000u); }
// packed f32x2 -> bf16x2 (RNE), single HW instruction
__device__ __forceinline__ uint cvtpk(float lo, float hi) {
    uint r;
    asm("v_cvt_pk_bf16_f32 %0, %1, %2" : "=v"(r) : "v"(lo), "v"(hi));
    return r;
}

typedef __attribute__((address_space(3))) uint lds_u32_t;
typedef __attribute__((address_space(1))) const uint glb_u32_t;
__device__ __forceinline__ void gl_lds16(const ushort* g, ushort* l) {
    __builtin_amdgcn_global_load_lds((glb_u32_t*)g, (lds_u32_t*)l, 16, 0, 0);
}

// ---------------------------------------------------------------------------
// convert qkv_w (768x256) and out_w (256x256) f32 -> bf16
// ---------------------------------------------------------------------------
__global__ __launch_bounds__(256)
void convert_w(const float* __restrict__ qw, const float* __restrict__ ow,
               ushort* __restrict__ wq, ushort* __restrict__ wo)
{
    const int e = (blockIdx.x * 256 + threadIdx.x) * 4;   // 262144 total
    if (e < 196608) {
        const float4 v = *(const float4*)(qw + e);
        uint2 w; w.x = cvtpk(v.x, v.y); w.y = cvtpk(v.z, v.w);
        *(uint2*)(wq + e) = w;
    } else {
        const int e2 = e - 196608;
        const float4 v = *(const float4*)(ow + e2);
        uint2 w; w.x = cvtpk(v.x, v.y); w.y = cvtpk(v.z, v.w);
        *(uint2*)(wo + e2) = w;
    }
}

// ---------------------------------------------------------------------------
// x (B,256,3136) f32 -> XT (B,3200,256) bf16 (transposed, N-major), FUSED
// with region-pool partial sums (deterministic, no atomics).
// ---------------------------------------------------------------------------
__global__ __launch_bounds__(256)
void convert_x(const float* __restrict__ x, ushort* __restrict__ xt,
               float* __restrict__ part)
{
    __shared__ float tile[64][65];
    const int p0 = blockIdx.x * 64, c0 = blockIdx.y * 64, b = blockIdx.z;
    const int tid = threadIdx.x;
    #pragma unroll
    for (int it = 0; it < 4; ++it) {
        const int slot = it * 256 + tid;
        const int c = slot >> 4, p4 = (slot & 15) << 2;
        const float4 v = *(const float4*)(x + ((size_t)b * Cn + c0 + c) * HWn + p0 + p4);
        tile[c][p4 + 0] = v.x; tile[c][p4 + 1] = v.y;
        tile[c][p4 + 2] = v.z; tile[c][p4 + 3] = v.w;
    }
    __syncthreads();
    #pragma unroll
    for (int it = 0; it < 4; ++it) {
        const int slot = it * 256 + tid;
        const int p = slot >> 4, c4 = (slot & 15) << 2;
        uint2 w;
        w.x = cvtpk(tile[c4 + 0][p], tile[c4 + 1][p]);
        w.y = cvtpk(tile[c4 + 2][p], tile[c4 + 3][p]);
        *(uint2*)(xt + ((size_t)b * NPn + p0 + p) * Cn + c0 + c4) = w;
    }
    // pooling partials: two 8-pixel run sums per thread
    {
        const int c = tid >> 2, q = tid & 3;
        float sA = 0.f, sB = 0.f;
        #pragma unroll
        for (int p = 0; p < 8; ++p) sA += tile[c][q * 16 + p];
        #pragma unroll
        for (int p = 0; p < 8; ++p) sB += tile[c][q * 16 + 8 + p];
        float* pp = part + ((((size_t)b * 4 + blockIdx.y) * 49 + blockIdx.x) * 64 + c) * 8 + q * 2;
        *(float2*)pp = make_float2(sA, sB);
    }
}

// ---------------------------------------------------------------------------
// reduce partials -> xr (B,256,49) f32 region means.
// ---------------------------------------------------------------------------
__global__ __launch_bounds__(256)
void reduce_pool(const float* __restrict__ part, float* __restrict__ xr)
{
    const int gid = blockIdx.x * 256 + threadIdx.x;   // 200704 = 784*256
    const int r = gid % NREGn;
    const int t = gid / NREGn;
    const int c = t % Cn, b = t / Cn;
    const int ry = r / 7, rx = r % 7;
    const float* pb = part + ((((size_t)b * 4 + (c >> 6)) * 49 + 7 * ry) * 64 + (c & 63)) * 8;
    float s = 0.f;
    #pragma unroll
    for (int j = 0; j < 7; ++j) {
        const int s0 = (rx - j + 7) % 7;
        s += pb[j * 512 + s0];
        if (s0 == 0) s += pb[j * 512 + 7];
    }
    xr[gid] = s * (1.0f / 64.0f);
}

// ---------------------------------------------------------------------------
// pooled q_r/k_r in f32 from pooled x: one output per thread
// ---------------------------------------------------------------------------
__global__ __launch_bounds__(256)
void qkr_gemm(const float* __restrict__ qw, const float* __restrict__ qb,
              const float* __restrict__ xr, float* __restrict__ qr,
              float* __restrict__ kr)
{
    const int gid = blockIdx.x * 256 + threadIdx.x;    // 401,408 = 16*512*49
    const int j = gid % NREGn;
    const int t = gid / NREGn;
    const int m = t & 511;
    const int b = t >> 9;
    const float* wr = qw + (size_t)m * Cn;
    const float* xb = xr + (size_t)b * Cn * NREGn + j;
    float s = 0.f;
    #pragma unroll 8
    for (int c = 0; c < Cn; ++c)
        s = fmaf(wr[c], xb[c * NREGn], s);
    s += qb[m];
    if (m < Cn) qr[((size_t)b * Cn + m) * NREGn + j] = s;
    else        kr[((size_t)b * Cn + (m - Cn)) * NREGn + j] = s;
}

// ---------------------------------------------------------------------------
// routing: a[i][j] = sum_c qr[b,c,i]*kr[b,c,j]; top-4 per row. grid (7,16)
// ---------------------------------------------------------------------------
__global__ __launch_bounds__(256)
void routing(const float* __restrict__ qr, const float* __restrict__ kr,
             int* __restrict__ idxo)
{
    const int ig = blockIdx.x, b = blockIdx.y;
    __shared__ float ksh[Cn][NREGn];        // 50 KB
    __shared__ float qsh[Cn][7];
    __shared__ float ar[7][NREGn];
    const float* qb = qr + (size_t)b * Cn * NREGn;
    const float* kb = kr + (size_t)b * Cn * NREGn;
    for (int e = threadIdx.x; e < Cn * NREGn; e += 256)
        ksh[e / NREGn][e % NREGn] = kb[e];             // coalesced stage
    for (int e = threadIdx.x; e < Cn * 7; e += 256)
        qsh[e / 7][e % 7] = qb[(e / 7) * NREGn + ig * 7 + (e % 7)];
    __syncthreads();
    for (int e = threadIdx.x; e < 7 * NREGn; e += 256) {
        const int il = e / NREGn, j = e % NREGn;
        float s = 0.f;
        for (int c = 0; c < Cn; ++c)
            s = fmaf(qsh[c][il], ksh[c][j], s);
        ar[il][j] = s;
    }
    __syncthreads();
    if (threadIdx.x < 7) {
        const int il = threadIdx.x;
        float bv0 = -3.0e38f, bv1 = -3.0e38f, bv2 = -3.0e38f, bv3 = -3.0e38f;
        int bi0 = 0, bi1 = 0, bi2 = 0, bi3 = 0;
        for (int j = 0; j < NREGn; ++j) {
            const float v = ar[il][j];
            if (v > bv3) {
                if (v > bv0)      { bv3=bv2; bi3=bi2; bv2=bv1; bi2=bi1; bv1=bv0; bi1=bi0; bv0=v; bi0=j; }
                else if (v > bv1) { bv3=bv2; bi3=bi2; bv2=bv1; bi2=bi1; bv1=v; bi1=j; }
                else if (v > bv2) { bv3=bv2; bi3=bi2; bv2=v; bi2=j; }
                else              { bv3=v; bi3=j; }
            }
        }
        int* o = idxo + ((size_t)b * NREGn + ig * 7 + il) * TOPKn;
        o[0] = bi0; o[1] = bi1; o[2] = bi2; o[3] = bi3;
    }
}

// ---------------------------------------------------------------------------
// bf16 MFMA GEMM, 128x128 tile, 4 waves, 2-phase double-buffered staging.
// XCD-swizzled grid. MODE 0: qkv -> q(scaled)/k seq + v -> VT.
// MODE 1: out proj -> f32 plane.
// ---------------------------------------------------------------------------
template<int MODE>
__global__ __launch_bounds__(256)
void gemm_mfma(const ushort* __restrict__ Wb, const float* __restrict__ bias,
               const ushort* __restrict__ Bt,
               ushort* __restrict__ oq, ushort* __restrict__ ok,
               ushort* __restrict__ ovt, float* __restrict__ of)
{
    constexpr int K = Cn;
    int bb, bx, by;
    {
        const int flat = blockIdx.x;
        if (MODE == 0) {                       // 2400 = 8*300 blocks
            const int sw = (flat & 7) * 300 + (flat >> 3);
            bb = sw / 150; const int r2 = sw % 150; bx = r2 / 6; by = r2 % 6;
        } else {                               // 800 = 8*100 blocks
            const int sw = (flat & 7) * 100 + (flat >> 3);
            bb = sw / 50;  const int r2 = sw % 50;  bx = r2 / 2; by = r2 % 2;
        }
    }
    const int n0 = bx * 128;
    const int m0 = by * 128;
    __shared__ ushort As[2][4096];
    __shared__ ushort Bs[2][4096];
    const int tid = threadIdx.x;
    const int wid = tid >> 6, lane = tid & 63;
    const int wm = wid >> 1, wn = wid & 1;
    const ushort* Bb = Bt + (size_t)bb * NPn * K;

    f32x4 acc[4][4];
    #pragma unroll
    for (int i = 0; i < 4; ++i)
        #pragma unroll
        for (int j = 0; j < 4; ++j)
            acc[i][j] = (f32x4){0.f, 0.f, 0.f, 0.f};

    const int cA = wid * 64 + lane;
    const int rowA = cA >> 2, koffA = (cA & 3) << 3;

    const ushort* wA0 = Wb + (size_t)(m0 + rowA) * K + koffA;
    const ushort* wA1 = Wb + (size_t)(m0 + rowA + 64) * K + koffA;
    const ushort* bB0 = Bb + (size_t)(n0 + rowA) * K + koffA;
    const ushort* bB1 = Bb + (size_t)(n0 + rowA + 64) * K + koffA;

#define STAGE(buf, k0)                                              \
    do {                                                            \
        gl_lds16(wA0 + (k0), &As[buf][wid * 512]);                  \
        gl_lds16(wA1 + (k0), &As[buf][2048 + wid * 512]);           \
        gl_lds16(bB0 + (k0), &Bs[buf][wid * 512]);                  \
        gl_lds16(bB1 + (k0), &Bs[buf][2048 + wid * 512]);           \
    } while (0)

    STAGE(0, 0);
    __syncthreads();
    int cur = 0;
    for (int k0 = 0; k0 < K; k0 += 32, cur ^= 1) {
        if (k0 + 32 < K) STAGE(cur ^ 1, k0 + 32);
        short8 a[4], b[4];
        #pragma unroll
        for (int i = 0; i < 4; ++i)
            a[i] = *(const short8*)(&As[cur][(wm * 64 + i * 16 + (lane & 15)) * 32 + ((lane >> 4) << 3)]);
        #pragma unroll
        for (int j = 0; j < 4; ++j)
            b[j] = *(const short8*)(&Bs[cur][(wn * 64 + j * 16 + (lane & 15)) * 32 + ((lane >> 4) << 3)]);
        #pragma unroll
        for (int i = 0; i < 4; ++i)
            #pragma unroll
            for (int j = 0; j < 4; ++j)
                acc[i][j] = __builtin_amdgcn_mfma_f32_16x16x32_bf16(a[i], b[j], acc[i][j], 0, 0, 0);
        __syncthreads();   // drains vmcnt (next-tile stage) + lgkm (our reads)
    }
#undef STAGE

    if (MODE == 0) {
        #pragma unroll
        for (int i = 0; i < 4; ++i) {
            const int m_base = m0 + wm * 64 + i * 16;
            const int which = m_base >> 8;                       // 0=q 1=k 2=v
            const int hh = (m_base >> 5) & 7;
            const int db = (m_base & 31) + ((lane >> 4) << 2);   // 0..28
            const float4 b4 = *(const float4*)(bias + m_base + ((lane >> 4) << 2));
            #pragma unroll
            for (int j = 0; j < 4; ++j) {
                const int n = n0 + wn * 64 + j * 16 + (lane & 15);
                if (n < HWn) {
                    const int py = n / 56, px = n % 56;
                    const int rr = (py >> 3) * 7 + (px >> 3);
                    const int ss = ((py & 7) << 3) + (px & 7);
                    if (which == 0) {
                        uint2 w;
                        w.x = cvtpk((acc[i][j][0] + b4.x) * QKSf, (acc[i][j][1] + b4.y) * QKSf);
                        w.y = cvtpk((acc[i][j][2] + b4.z) * QKSf, (acc[i][j][3] + b4.w) * QKSf);
                        *(uint2*)(oq + (((size_t)bb * NHn + hh) * HWn + rr * 64 + ss) * 32 + db) = w;
                    } else if (which == 1) {
                        uint2 w;
                        w.x = cvtpk(acc[i][j][0] + b4.x, acc[i][j][1] + b4.y);
                        w.y = cvtpk(acc[i][j][2] + b4.z, acc[i][j][3] + b4.w);
                        *(uint2*)(ok + (((size_t)bb * NHn + hh) * HWn + rr * 64 + ss) * 32 + db) = w;
                    } else {
                        const size_t vtb = ((size_t)(bb * NHn + hh) * 32 + db) * HWn + rr * 64 + ss;
                        const uint lo = cvtpk(acc[i][j][0] + b4.x, acc[i][j][1] + b4.y);
                        const uint hi = cvtpk(acc[i][j][2] + b4.z, acc[i][j][3] + b4.w);
                        ovt[vtb + 0 * HWn] = (ushort)lo;
                        ovt[vtb + 1 * HWn] = (ushort)(lo >> 16);
                        ovt[vtb + 2 * HWn] = (ushort)hi;
                        ovt[vtb + 3 * HWn] = (ushort)(hi >> 16);
                    }
                }
            }
        }
    } else {
        #pragma unroll
        for (int i = 0; i < 4; ++i) {
            const int mb = m0 + wm * 64 + i * 16 + ((lane >> 4) << 2);
            const float4 b4 = *(const float4*)(bias + mb);
            #pragma unroll
            for (int j = 0; j < 4; ++j) {
                const int n = n0 + wn * 64 + j * 16 + (lane & 15);
                if (n < HWn) {
                    const int rr = n >> 6, ss = n & 63;
                    const int py = (rr / 7) * 8 + (ss >> 3);
                    const int px = (rr % 7) * 8 + (ss & 7);
                    float* od = of + ((size_t)bb * Cn + mb) * HWn + py * 56 + px;
                    od[0 * HWn] = acc[i][j][0] + b4.x;
                    od[1 * HWn] = acc[i][j][1] + b4.y;
                    od[2 * HWn] = acc[i][j][2] + b4.z;
                    od[3 * HWn] = acc[i][j][3] + b4.w;
                }
            }
        }
    }
}

// ---------------------------------------------------------------------------
// LePE: depthwise 5x5 SAME conv, 8-wide strip per thread, region-ordered I/O.
// ---------------------------------------------------------------------------
__global__ __launch_bounds__(256)
void lepe(const ushort* __restrict__ vt, const float* __restrict__ lw,
          const float* __restrict__ lb, ushort* __restrict__ lbuf)
{
    const int gid = blockIdx.x * 256 + threadIdx.x;   // 1,605,632 = 6272*256
    const int plane = gid / 392;                      // b*256 + c
    const int within = gid - plane * 392;
    const int row = within / 7;                       // 0..55
    const int sx  = within - row * 7;                 // 0..6
    const int px0 = sx * 8;
    const int c = plane & 255;
    const ushort* vp = vt + (size_t)plane * HWn;
    const float* wc = lw + c * 25;

    float wreg[25];
    #pragma unroll
    for (int i = 0; i < 25; ++i) wreg[i] = wc[i];

    float acc[8];
    const float bias = lb[c];
    #pragma unroll
    for (int j = 0; j < 8; ++j) acc[j] = bias;

    #pragma unroll
    for (int kh = 0; kh < 5; ++kh) {
        const int iy = row + kh - 2;
        if (iy < 0 || iy >= Hn) continue;
        const int ry = iy >> 3, il = iy & 7;
        const ushort* rp = vp + (ry * 7 + sx) * 64 + il * 8;
        const uint  a = *(const uint*)(rp - 64 + 6);
        const uint4 M = *(const uint4*)(rp);
        const uint  e = *(const uint*)(rp + 64);
        float w[12];
        w[0]  = (px0 >= 2)      ? b2fl(a)   : 0.f;
        w[1]  = (px0 >= 1)      ? b2fh(a)   : 0.f;
        w[2]  = b2fl(M.x); w[3]  = b2fh(M.x);
        w[4]  = b2fl(M.y); w[5]  = b2fh(M.y);
        w[6]  = b2fl(M.z); w[7]  = b2fh(M.z);
        w[8]  = b2fl(M.w); w[9]  = b2fh(M.w);
        w[10] = (px0 + 8 < Wn)  ? b2fl(e)   : 0.f;
        w[11] = (px0 + 9 < Wn)  ? b2fh(e)   : 0.f;
        #pragma unroll
        for (int kw = 0; kw < 5; ++kw) {
            const float ww = wreg[kh * 5 + kw];
            #pragma unroll
            for (int j = 0; j < 8; ++j)
                acc[j] = fmaf(w[j + kw], ww, acc[j]);
        }
    }
    ushort* op = lbuf + (size_t)plane * HWn + ((row >> 3) * 7 + sx) * 64 + (row & 7) * 8;
    uint2 wa, wb;
    wa.x = cvtpk(acc[0], acc[1]); wa.y = cvtpk(acc[2], acc[3]);
    wb.x = cvtpk(acc[4], acc[5]); wb.y = cvtpk(acc[6], acc[7]);
    *(uint2*)(op)     = wa;
    *(uint2*)(op + 4) = wb;
}

// ---------------------------------------------------------------------------
// MFMA attention: r11 launch config (256 thr, (256,2), 1568 blocks — the
// proven 104-VGPR regalloc sweet spot) + softmax shuffle-trim: in-lane
// partial denominator (corr-rescaled on rare defer-max), lane-local max in
// the __all defer check, max-reduce shuffles inside the rare branch, one
// cross-lane sum per qt at the end.
// ---------------------------------------------------------------------------
__global__ __launch_bounds__(256, 2)
void attention3(const ushort* __restrict__ qs, const ushort* __restrict__ ks,
                const ushort* __restrict__ vt, const int* __restrict__ idxp,
                const ushort* __restrict__ lep, ushort* __restrict__ yt)
{
    const int flat = blockIdx.x;                  // 1568 = 8*196
    const int sw = (flat & 7) * 196 + (flat >> 3);
    const int b = sw / 98;
    const int rem = sw % 98;
    const int r = rem % 49;
    const int wid = threadIdx.x >> 6, lane = threadIdx.x & 63;
    const int h = (rem / 49) * 4 + wid;
    const int col = lane & 15, g = lane >> 4;
    __shared__ ushort plds_all[4][4096];          // 8KB per wave
    ushort* pw = plds_all[wid];

    const size_t hb = ((size_t)b * NHn + h) * HWn;
    const size_t vtb = (size_t)(b * NHn + h) * 32;

    short8 qf[4];
    #pragma unroll
    for (int qt = 0; qt < 4; ++qt)
        qf[qt] = *(const short8*)(qs + (hb + (size_t)r * 64 + qt * 16 + col) * 32 + g * 8);

    f32x4 o[4][2];
    #pragma unroll
    for (int qt = 0; qt < 4; ++qt) {
        o[qt][0] = (f32x4){0.f, 0.f, 0.f, 0.f};
        o[qt][1] = (f32x4){0.f, 0.f, 0.f, 0.f};
    }
    float mrow[4] = {-3.0e38f, -3.0e38f, -3.0e38f, -3.0e38f};
    float psum[4] = {0.f, 0.f, 0.f, 0.f};   // in-lane partial denominator

    const int* ip = idxp + ((size_t)b * NREGn + r) * TOPKn;
    const int4 i4 = *(const int4*)ip;
    const int idxs[4] = {i4.x, i4.y, i4.z, i4.w};

    short8 kfA[4], vfA[4];   // vf[dt*2+kc]
    {
        const int rr = idxs[0];
        #pragma unroll
        for (int kt = 0; kt < 4; ++kt)
            kfA[kt] = *(const short8*)(ks + (hb + (size_t)rr * 64 + kt * 16 + col) * 32 + g * 8);
        #pragma unroll
        for (int dt = 0; dt < 2; ++dt)
            #pragma unroll
            for (int kc = 0; kc < 2; ++kc)
                vfA[dt * 2 + kc] = *(const short8*)(vt + (vtb + dt * 16 + col) * HWn
                                                    + (size_t)rr * 64 + kc * 32 + g * 8);
    }

    #pragma unroll
    for (int t = 0; t < TOPKn; ++t) {
        short8 kfB[4], vfB[4];
        if (t < 3) {   // prefetch next region while computing this one
            const int rr = idxs[t + 1];
            #pragma unroll
            for (int kt = 0; kt < 4; ++kt)
                kfB[kt] = *(const short8*)(ks + (hb + (size_t)rr * 64 + kt * 16 + col) * 32 + g * 8);
            #pragma unroll
            for (int dt = 0; dt < 2; ++dt)
                #pragma unroll
                for (int kc = 0; kc < 2; ++kc)
                    vfB[dt * 2 + kc] = *(const short8*)(vt + (vtb + dt * 16 + col) * HWn
                                                         + (size_t)rr * 64 + kc * 32 + g * 8);
        }

        #pragma unroll
        for (int qt = 0; qt < 4; ++qt) {
            f32x4 s[4];
            #pragma unroll
            for (int kt = 0; kt < 4; ++kt)
                s[kt] = __builtin_amdgcn_mfma_f32_16x16x32_bf16(
                    kfA[kt], qf[qt], (f32x4){0.f, 0.f, 0.f, 0.f}, 0, 0, 0);

            // lane-local max (no cross-lane reduce in steady state)
            float mx = s[0][0];
            #pragma unroll
            for (int kt = 0; kt < 4; ++kt)
                #pragma unroll
                for (int e = 0; e < 4; ++e)
                    mx = fmaxf(mx, s[kt][e]);
            // defer-max: rescale only when some lane's local max grew by > 8
            if (!__all(mx - mrow[qt] <= 8.f)) {
                float mr = mx;
                mr = fmaxf(mr, __shfl_xor(mr, 16));
                mr = fmaxf(mr, __shfl_xor(mr, 32));
                const float mnew = fmaxf(mrow[qt], mr);
                const float corr = exp2f(mrow[qt] - mnew);
                mrow[qt] = mnew;
                psum[qt] *= corr;
                #pragma unroll
                for (int reg = 0; reg < 4; ++reg) {
                    const float cr = __shfl(corr, g * 4 + reg);
                    o[qt][0][reg] *= cr;
                    o[qt][1][reg] *= cr;
                }
            }
            float ls = 0.f;
            #pragma unroll
            for (int kt = 0; kt < 4; ++kt)
                #pragma unroll
                for (int e = 0; e < 4; ++e) {
                    const float p = exp2f(s[kt][e] - mrow[qt]);
                    s[kt][e] = p; ls += p;
                }
            psum[qt] += ls;
            const int qrow = qt * 16 + col;
            const int swz = (qrow & 7) << 4;
            #pragma unroll
            for (int kt = 0; kt < 4; ++kt) {
                uint2 pk;
                pk.x = cvtpk(s[kt][0], s[kt][1]);
                pk.y = cvtpk(s[kt][2], s[kt][3]);
                const int byt = (qrow * 128 + kt * 32 + g * 8) ^ swz;
                *(uint2*)((char*)pw + byt) = pk;
            }
        }

        #pragma unroll
        for (int kc = 0; kc < 2; ++kc)
            #pragma unroll
            for (int qt = 0; qt < 4; ++qt) {
                const int qrow = qt * 16 + col;
                const int byt = (qrow * 128 + kc * 64 + g * 16) ^ ((qrow & 7) << 4);
                const short8 pf = *(const short8*)((const char*)pw + byt);
                o[qt][0] = __builtin_amdgcn_mfma_f32_16x16x32_bf16(pf, vfA[0 * 2 + kc], o[qt][0], 0, 0, 0);
                o[qt][1] = __builtin_amdgcn_mfma_f32_16x16x32_bf16(pf, vfA[1 * 2 + kc], o[qt][1], 0, 0, 0);
            }

        if (t < 3) {
            #pragma unroll
            for (int i = 0; i < 4; ++i) { kfA[i] = kfB[i]; vfA[i] = vfB[i]; }
        }
    }

    // denominator: one cross-lane reduction per qt, then normalize + bounce O
    #pragma unroll
    for (int qt = 0; qt < 4; ++qt) {
        float ps = psum[qt];
        ps += __shfl_xor(ps, 16);
        ps += __shfl_xor(ps, 32);
        const float linv = 1.0f / ps;
        #pragma unroll
        for (int reg = 0; reg < 4; ++reg) {
            const float li = __shfl(linv, g * 4 + reg);
            const int row = qt * 16 + g * 4 + reg;
            const int swz = ((row >> 1) & 3) << 4;
            const uint pk = cvtpk(o[qt][0][reg] * li, o[qt][1][reg] * li);
            const int byt0 = (row * 64 + col * 2) ^ swz;
            const int byt1 = (row * 64 + (16 + col) * 2) ^ swz;
            *(ushort*)((char*)pw + byt0) = (ushort)pk;
            *(ushort*)((char*)pw + byt1) = (ushort)(pk >> 16);
        }
    }
    const ushort* lp = lep + ((size_t)b * Cn + h * 32) * HWn + (size_t)r * 64 + lane;
    ushort* yp = yt + ((size_t)b * NPn + (size_t)r * 64 + lane) * Cn + h * 32;
    const int swl = ((lane >> 1) & 3) << 4;
    #pragma unroll
    for (int c4 = 0; c4 < 8; ++c4) {
        const int byt = (lane * 64 + c4 * 8) ^ swl;
        const ushort4 ov = *(const ushort4*)((const char*)pw + byt);
        const float a0 = b2f(ov.x) + b2f(lp[(size_t)(c4 * 4 + 0) * HWn]);
        const float a1 = b2f(ov.y) + b2f(lp[(size_t)(c4 * 4 + 1) * HWn]);
        const float a2 = b2f(ov.z) + b2f(lp[(size_t)(c4 * 4 + 2) * HWn]);
        const float a3 = b2f(ov.w) + b2f(lp[(size_t)(c4 * 4 + 3) * HWn]);
        uint2 w4; w4.x = cvtpk(a0, a1); w4.y = cvtpk(a2, a3);
        *(uint2*)(yp + c4 * 4) = w4;
    }
}

// ---------------------------------------------------------------------------
extern "C" void kernel_launch(void* const* d_in, const int* in_sizes, int n_in,
                              void* d_out, int out_size, void* d_ws, size_t ws_size,
                              hipStream_t stream)
{
    const float* x      = (const float*)d_in[0];
    const float* qkv_w  = (const float*)d_in[1];
    const float* qkv_b  = (const float*)d_in[2];
    const float* lepe_w = (const float*)d_in[3];
    const float* lepe_b = (const float*)d_in[4];
    const float* out_w  = (const float*)d_in[5];
    const float* out_b  = (const float*)d_in[6];
    float* out = (float*)d_out;

    char* ws = (char*)d_ws;
    ushort* XT = (ushort*)(ws);                                  // 26,214,400
    ushort* YT = (ushort*)(ws + 26214400);                       // 26,214,400
    ushort* QS = (ushort*)(ws + 52428800);                       // 25,690,112
    ushort* KS = (ushort*)(ws + 78118912);                       // 25,690,112
    ushort* VT = (ushort*)(ws + 103809024);                      // 25,690,112
    ushort* LB = (ushort*)(ws + 129499136);                      // 25,690,112
    ushort* WQ = (ushort*)(ws + 155189248);                      // 393,216
    ushort* WO = (ushort*)(ws + 155582464);                      // 131,072
    float*  XR = (float*)(ws + 155713536);                       // 802,816
    float*  QR = (float*)(ws + 156516352);                       // 802,816
    float*  KR = (float*)(ws + 157319168);                       // 802,816
    int*   IDX = (int*)(ws + 158121984);                         // 12,544
    float* PART = (float*)(ws + 158134528);                      // 6,422,528

    convert_w<<<256, 256, 0, stream>>>(qkv_w, out_w, WQ, WO);
    convert_x<<<dim3(49, 4, 16), 256, 0, stream>>>(x, XT, PART);
    reduce_pool<<<784, 256, 0, stream>>>(PART, XR);
    qkr_gemm<<<1568, 256, 0, stream>>>(qkv_w, qkv_b, XR, QR, KR);
    routing<<<dim3(7, 16), 256, 0, stream>>>(QR, KR, IDX);
    gemm_mfma<0><<<2400, 256, 0, stream>>>(WQ, qkv_b, XT, QS, KS, VT, nullptr);
    lepe<<<6272, 256, 0, stream>>>(VT, lepe_w, lepe_b, LB);
    attention3<<<1568, 256, 0, stream>>>(QS, KS, VT, IDX, LB, YT);
    gemm_mfma<1><<<800, 256, 0, stream>>>(WO, out_b, YT, nullptr, nullptr, nullptr, out);
}

// Round 14
// 233.610 us; speedup vs baseline: 1.7712x; 1.0414x over previous
//
#include <hip/hip_runtime.h>

typedef __attribute__((ext_vector_type(8))) short short8;
typedef __attribute__((ext_vector_type(4))) float f32x4;
typedef unsigned int uint;

constexpr int Bn    = 16;
constexpr int Cn    = 256;
constexpr int Hn    = 56;
constexpr int Wn    = 56;
constexpr int HWn   = Hn * Wn;       // 3136
constexpr int NPn   = 3200;          // padded N (25 * 128)
constexpr int NHn   = 8;
constexpr int RWn   = 7;
constexpr int NREGn = 49;
constexpr int TOPKn = 4;
// scale folded into stored q: 256^-0.5 * log2(e)  (softmax done in base 2)
constexpr float QKSf = 0.0625f * 1.44269504088896f;

__device__ __forceinline__ float b2f(ushort u) { return __builtin_bit_cast(float, (uint)u << 16); }
__device__ __forceinline__ float b2fl(uint u) { return __builtin_bit_cast(float, u << 16); }
__device__ __forceinline__ float b2fh(uint u) { return __builtin_bit_cast(float, u & 0xffff0000u); }
// packed f32x2 -> bf16x2 (RNE), single HW instruction
__device__ __forceinline__ uint cvtpk(float lo, float hi) {
    uint r;
    asm("v_cvt_pk_bf16_f32 %0, %1, %2" : "=v"(r) : "v"(lo), "v"(hi));
    return r;
}

typedef __attribute__((address_space(3))) uint lds_u32_t;
typedef __attribute__((address_space(1))) const uint glb_u32_t;
__device__ __forceinline__ void gl_lds16(const ushort* g, ushort* l) {
    __builtin_amdgcn_global_load_lds((glb_u32_t*)g, (lds_u32_t*)l, 16, 0, 0);
}

// ---------------------------------------------------------------------------
// convert qkv_w (768x256) and out_w (256x256) f32 -> bf16
// ---------------------------------------------------------------------------
__global__ __launch_bounds__(256)
void convert_w(const float* __restrict__ qw, const float* __restrict__ ow,
               ushort* __restrict__ wq, ushort* __restrict__ wo)
{
    const int e = (blockIdx.x * 256 + threadIdx.x) * 4;   // 262144 total
    if (e < 196608) {
        const float4 v = *(const float4*)(qw + e);
        uint2 w; w.x = cvtpk(v.x, v.y); w.y = cvtpk(v.z, v.w);
        *(uint2*)(wq + e) = w;
    } else {
        const int e2 = e - 196608;
        const float4 v = *(const float4*)(ow + e2);
        uint2 w; w.x = cvtpk(v.x, v.y); w.y = cvtpk(v.z, v.w);
        *(uint2*)(wo + e2) = w;
    }
}

// ---------------------------------------------------------------------------
// pool x: (B,256,3136) f32 -> xr (B,256,49) f32  (8x8 region means)
// Runs first: cold-reads x once, warming L3 for gemm<0>'s direct x reads.
// ---------------------------------------------------------------------------
__global__ __launch_bounds__(256)
void pool_x(const float* __restrict__ x, float* __restrict__ xr)
{
    const int gid = blockIdx.x * 256 + threadIdx.x;
    if (gid >= Bn * Cn * NREGn) return;
    const int r = gid % NREGn;
    const int t = gid / NREGn;
    const int c = t % Cn, b = t / Cn;
    const float* plane = x + ((size_t)b * Cn + c) * HWn + (r / RWn) * 8 * Wn + (r % RWn) * 8;
    float s = 0.f;
    #pragma unroll
    for (int p = 0; p < 8; ++p) {
        const float4 a  = *(const float4*)(plane + p * Wn);
        const float4 b4 = *(const float4*)(plane + p * Wn + 4);
        s += a.x + a.y + a.z + a.w + b4.x + b4.y + b4.z + b4.w;
    }
    xr[gid] = s * (1.0f / 64.0f);
}

// ---------------------------------------------------------------------------
// pooled q_r/k_r in f32 from pooled x: one output per thread
// ---------------------------------------------------------------------------
__global__ __launch_bounds__(256)
void qkr_gemm(const float* __restrict__ qw, const float* __restrict__ qb,
              const float* __restrict__ xr, float* __restrict__ qr,
              float* __restrict__ kr)
{
    const int gid = blockIdx.x * 256 + threadIdx.x;    // 401,408 = 16*512*49
    const int j = gid % NREGn;
    const int t = gid / NREGn;
    const int m = t & 511;
    const int b = t >> 9;
    const float* wr = qw + (size_t)m * Cn;
    const float* xb = xr + (size_t)b * Cn * NREGn + j;
    float s = 0.f;
    #pragma unroll 8
    for (int c = 0; c < Cn; ++c)
        s = fmaf(wr[c], xb[c * NREGn], s);
    s += qb[m];
    if (m < Cn) qr[((size_t)b * Cn + m) * NREGn + j] = s;
    else        kr[((size_t)b * Cn + (m - Cn)) * NREGn + j] = s;
}

// ---------------------------------------------------------------------------
// routing: a[i][j] = sum_c qr[b,c,i]*kr[b,c,j]; top-4 per row. grid (7,16)
// ---------------------------------------------------------------------------
__global__ __launch_bounds__(256)
void routing(const float* __restrict__ qr, const float* __restrict__ kr,
             int* __restrict__ idxo)
{
    const int ig = blockIdx.x, b = blockIdx.y;
    __shared__ float ksh[Cn][NREGn];        // 50 KB
    __shared__ float qsh[Cn][7];
    __shared__ float ar[7][NREGn];
    const float* qb = qr + (size_t)b * Cn * NREGn;
    const float* kb = kr + (size_t)b * Cn * NREGn;
    for (int e = threadIdx.x; e < Cn * NREGn; e += 256)
        ksh[e / NREGn][e % NREGn] = kb[e];             // coalesced stage
    for (int e = threadIdx.x; e < Cn * 7; e += 256)
        qsh[e / 7][e % 7] = qb[(e / 7) * NREGn + ig * 7 + (e % 7)];
    __syncthreads();
    for (int e = threadIdx.x; e < 7 * NREGn; e += 256) {
        const int il = e / NREGn, j = e % NREGn;
        float s = 0.f;
        for (int c = 0; c < Cn; ++c)
            s = fmaf(qsh[c][il], ksh[c][j], s);
        ar[il][j] = s;
    }
    __syncthreads();
    if (threadIdx.x < 7) {
        const int il = threadIdx.x;
        float bv0 = -3.0e38f, bv1 = -3.0e38f, bv2 = -3.0e38f, bv3 = -3.0e38f;
        int bi0 = 0, bi1 = 0, bi2 = 0, bi3 = 0;
        for (int j = 0; j < NREGn; ++j) {
            const float v = ar[il][j];
            if (v > bv3) {
                if (v > bv0)      { bv3=bv2; bi3=bi2; bv2=bv1; bi2=bi1; bv1=bv0; bi1=bi0; bv0=v; bi0=j; }
                else if (v > bv1) { bv3=bv2; bi3=bi2; bv2=bv1; bi2=bi1; bv1=v; bi1=j; }
                else if (v > bv2) { bv3=bv2; bi3=bi2; bv2=v; bi2=j; }
                else              { bv3=v; bi3=j; }
            }
        }
        int* o = idxo + ((size_t)b * NREGn + ig * 7 + il) * TOPKn;
        o[0] = bi0; o[1] = bi1; o[2] = bi2; o[3] = bi3;
    }
}

// ---------------------------------------------------------------------------
// bf16 MFMA GEMM, 128x128 tile, 4 waves, 2-phase double-buffered staging.
// XCD-swizzled grid.
// MODE 0: B read DIRECTLY from x (f32), converted inline to bf16 into a
//         BKP=40-padded LDS tile (80B rows: 16B-aligned b128, low-conflict);
//         outputs q(scaled)/k seq + v -> VT. Lane map: n consecutive ->
//         coalesced dword loads; pad cols n>=HWn clamp-read (discarded).
// MODE 1: B = YT bf16 via global_load_lds (unchanged); out proj -> f32 plane.
// ---------------------------------------------------------------------------
template<int MODE>
__global__ __launch_bounds__(256)
void gemm_mfma(const ushort* __restrict__ Wb, const float* __restrict__ bias,
               const ushort* __restrict__ Bt, const float* __restrict__ Xf,
               ushort* __restrict__ oq, ushort* __restrict__ ok,
               ushort* __restrict__ ovt, float* __restrict__ of)
{
    constexpr int K = Cn;
    constexpr int BSTR = (MODE == 0) ? 80 : 64;     // B LDS row stride, bytes
    int bb, bx, by;
    {
        const int flat = blockIdx.x;
        if (MODE == 0) {                       // 2400 = 8*300 blocks
            const int sw = (flat & 7) * 300 + (flat >> 3);
            bb = sw / 150; const int r2 = sw % 150; bx = r2 / 6; by = r2 % 6;
        } else {                               // 800 = 8*100 blocks
            const int sw = (flat & 7) * 100 + (flat >> 3);
            bb = sw / 50;  const int r2 = sw % 50;  bx = r2 / 2; by = r2 % 2;
        }
    }
    const int n0 = bx * 128;
    const int m0 = by * 128;
    __shared__ ushort As[2][4096];
    __shared__ ushort Bs[2][(MODE == 0) ? 5120 : 4096];
    const int tid = threadIdx.x;
    const int wid = tid >> 6, lane = tid & 63;
    const int wm = wid >> 1, wn = wid & 1;

    f32x4 acc[4][4];
    #pragma unroll
    for (int i = 0; i < 4; ++i)
        #pragma unroll
        for (int j = 0; j < 4; ++j)
            acc[i][j] = (f32x4){0.f, 0.f, 0.f, 0.f};

    const int cA = wid * 64 + lane;
    const int rowA = cA >> 2, koffA = (cA & 3) << 3;

    const ushort* wA0 = Wb + (size_t)(m0 + rowA) * K + koffA;
    const ushort* wA1 = Wb + (size_t)(m0 + rowA + 64) * K + koffA;

    // MODE 1 B source pointers
    const ushort* bB0 = nullptr; const ushort* bB1 = nullptr;
    if constexpr (MODE == 1) {
        const ushort* Bb = Bt + (size_t)bb * NPn * K;
        bB0 = Bb + (size_t)(n0 + rowA) * K + koffA;
        bB1 = Bb + (size_t)(n0 + rowA + 64) * K + koffA;
    }
    // MODE 0 B source: x f32, n-consecutive lanes, kh = upper/lower 16 k-rows
    const float* xs = nullptr;
    const int nl = tid & 127, kh = tid >> 7;
    if constexpr (MODE == 0) {
        const int nn = n0 + nl;
        const int nc = nn < HWn ? nn : (HWn - 1);   // clamp: pad cols discarded
        xs = Xf + (size_t)bb * Cn * HWn + (size_t)kh * 16 * HWn + nc;
    }
    float fB[16];

#define STAGEA(buf, k0)                                             \
    do {                                                            \
        gl_lds16(wA0 + (k0), &As[buf][wid * 512]);                  \
        gl_lds16(wA1 + (k0), &As[buf][2048 + wid * 512]);           \
    } while (0)
#define STAGEB1(buf, k0)                                            \
    do {                                                            \
        gl_lds16(bB0 + (k0), &Bs[buf][wid * 512]);                  \
        gl_lds16(bB1 + (k0), &Bs[buf][2048 + wid * 512]);           \
    } while (0)
#define LOADB0(k0)                                                  \
    do {                                                            \
        _Pragma("unroll")                                           \
        for (int j = 0; j < 16; ++j)                                \
            fB[j] = xs[(size_t)((k0) + j) * HWn];                   \
    } while (0)
#define WRITEB0(buf)                                                \
    do {                                                            \
        uint4 wv0, wv1;                                             \
        wv0.x = cvtpk(fB[0], fB[1]);   wv0.y = cvtpk(fB[2], fB[3]); \
        wv0.z = cvtpk(fB[4], fB[5]);   wv0.w = cvtpk(fB[6], fB[7]); \
        wv1.x = cvtpk(fB[8], fB[9]);   wv1.y = cvtpk(fB[10], fB[11]); \
        wv1.z = cvtpk(fB[12], fB[13]); wv1.w = cvtpk(fB[14], fB[15]); \
        char* bp = (char*)&Bs[buf][0] + nl * 80 + kh * 32;          \
        *(uint4*)bp = wv0;                                          \
        *(uint4*)(bp + 16) = wv1;                                   \
    } while (0)

    // prologue: stage tile 0
    if constexpr (MODE == 0) LOADB0(0);
    STAGEA(0, 0);
    if constexpr (MODE == 1) STAGEB1(0, 0);
    if constexpr (MODE == 0) WRITEB0(0);
    __syncthreads();

    int cur = 0;
    for (int k0 = 0; k0 < K; k0 += 32, cur ^= 1) {
        const bool more = (k0 + 32 < K);
        if (more) {
            if constexpr (MODE == 0) LOADB0(k0 + 32);
            STAGEA(cur ^ 1, k0 + 32);
            if constexpr (MODE == 1) STAGEB1(cur ^ 1, k0 + 32);
        }
        short8 a[4], b[4];
        #pragma unroll
        for (int i = 0; i < 4; ++i)
            a[i] = *(const short8*)(&As[cur][(wm * 64 + i * 16 + (lane & 15)) * 32 + ((lane >> 4) << 3)]);
        #pragma unroll
        for (int j = 0; j < 4; ++j)
            b[j] = *(const short8*)((const char*)&Bs[cur][0]
                        + (wn * 64 + j * 16 + (lane & 15)) * BSTR + ((lane >> 4) << 4));
        #pragma unroll
        for (int i = 0; i < 4; ++i)
            #pragma unroll
            for (int j = 0; j < 4; ++j)
                acc[i][j] = __builtin_amdgcn_mfma_f32_16x16x32_bf16(a[i], b[j], acc[i][j], 0, 0, 0);
        if (more) { if constexpr (MODE == 0) WRITEB0(cur ^ 1); }
        __syncthreads();   // drains vmcnt + lgkm; fences both LDS buffers
    }
#undef STAGEA
#undef STAGEB1
#undef LOADB0
#undef WRITEB0

    if (MODE == 0) {
        #pragma unroll
        for (int i = 0; i < 4; ++i) {
            const int m_base = m0 + wm * 64 + i * 16;
            const int which = m_base >> 8;                       // 0=q 1=k 2=v
            const int hh = (m_base >> 5) & 7;
            const int db = (m_base & 31) + ((lane >> 4) << 2);   // 0..28
            const float4 b4 = *(const float4*)(bias + m_base + ((lane >> 4) << 2));
            #pragma unroll
            for (int j = 0; j < 4; ++j) {
                const int n = n0 + wn * 64 + j * 16 + (lane & 15);
                if (n < HWn) {
                    const int py = n / 56, px = n % 56;
                    const int rr = (py >> 3) * 7 + (px >> 3);
                    const int ss = ((py & 7) << 3) + (px & 7);
                    if (which == 0) {
                        uint2 w;
                        w.x = cvtpk((acc[i][j][0] + b4.x) * QKSf, (acc[i][j][1] + b4.y) * QKSf);
                        w.y = cvtpk((acc[i][j][2] + b4.z) * QKSf, (acc[i][j][3] + b4.w) * QKSf);
                        *(uint2*)(oq + (((size_t)bb * NHn + hh) * HWn + rr * 64 + ss) * 32 + db) = w;
                    } else if (which == 1) {
                        uint2 w;
                        w.x = cvtpk(acc[i][j][0] + b4.x, acc[i][j][1] + b4.y);
                        w.y = cvtpk(acc[i][j][2] + b4.z, acc[i][j][3] + b4.w);
                        *(uint2*)(ok + (((size_t)bb * NHn + hh) * HWn + rr * 64 + ss) * 32 + db) = w;
                    } else {
                        const size_t vtb = ((size_t)(bb * NHn + hh) * 32 + db) * HWn + rr * 64 + ss;
                        const uint lo = cvtpk(acc[i][j][0] + b4.x, acc[i][j][1] + b4.y);
                        const uint hi = cvtpk(acc[i][j][2] + b4.z, acc[i][j][3] + b4.w);
                        ovt[vtb + 0 * HWn] = (ushort)lo;
                        ovt[vtb + 1 * HWn] = (ushort)(lo >> 16);
                        ovt[vtb + 2 * HWn] = (ushort)hi;
                        ovt[vtb + 3 * HWn] = (ushort)(hi >> 16);
                    }
                }
            }
        }
    } else {
        #pragma unroll
        for (int i = 0; i < 4; ++i) {
            const int mb = m0 + wm * 64 + i * 16 + ((lane >> 4) << 2);
            const float4 b4 = *(const float4*)(bias + mb);
            #pragma unroll
            for (int j = 0; j < 4; ++j) {
                const int n = n0 + wn * 64 + j * 16 + (lane & 15);
                if (n < HWn) {
                    const int rr = n >> 6, ss = n & 63;
                    const int py = (rr / 7) * 8 + (ss >> 3);
                    const int px = (rr % 7) * 8 + (ss & 7);
                    float* od = of + ((size_t)bb * Cn + mb) * HWn + py * 56 + px;
                    od[0 * HWn] = acc[i][j][0] + b4.x;
                    od[1 * HWn] = acc[i][j][1] + b4.y;
                    od[2 * HWn] = acc[i][j][2] + b4.z;
                    od[3 * HWn] = acc[i][j][3] + b4.w;
                }
            }
        }
    }
}

// ---------------------------------------------------------------------------
// LePE: depthwise 5x5 SAME conv, 8-wide strip per thread, region-ordered I/O.
// ---------------------------------------------------------------------------
__global__ __launch_bounds__(256)
void lepe(const ushort* __restrict__ vt, const float* __restrict__ lw,
          const float* __restrict__ lb, ushort* __restrict__ lbuf)
{
    const int gid = blockIdx.x * 256 + threadIdx.x;   // 1,605,632 = 6272*256
    const int plane = gid / 392;                      // b*256 + c
    const int within = gid - plane * 392;
    const int row = within / 7;                       // 0..55
    const int sx  = within - row * 7;                 // 0..6
    const int px0 = sx * 8;
    const int c = plane & 255;
    const ushort* vp = vt + (size_t)plane * HWn;
    const float* wc = lw + c * 25;

    float wreg[25];
    #pragma unroll
    for (int i = 0; i < 25; ++i) wreg[i] = wc[i];

    float acc[8];
    const float bias = lb[c];
    #pragma unroll
    for (int j = 0; j < 8; ++j) acc[j] = bias;

    #pragma unroll
    for (int kh = 0; kh < 5; ++kh) {
        const int iy = row + kh - 2;
        if (iy < 0 || iy >= Hn) continue;
        const int ry = iy >> 3, il = iy & 7;
        const ushort* rp = vp + (ry * 7 + sx) * 64 + il * 8;
        const uint  a = *(const uint*)(rp - 64 + 6);
        const uint4 M = *(const uint4*)(rp);
        const uint  e = *(const uint*)(rp + 64);
        float w[12];
        w[0]  = (px0 >= 2)      ? b2fl(a)   : 0.f;
        w[1]  = (px0 >= 1)      ? b2fh(a)   : 0.f;
        w[2]  = b2fl(M.x); w[3]  = b2fh(M.x);
        w[4]  = b2fl(M.y); w[5]  = b2fh(M.y);
        w[6]  = b2fl(M.z); w[7]  = b2fh(M.z);
        w[8]  = b2fl(M.w); w[9]  = b2fh(M.w);
        w[10] = (px0 + 8 < Wn)  ? b2fl(e)   : 0.f;
        w[11] = (px0 + 9 < Wn)  ? b2fh(e)   : 0.f;
        #pragma unroll
        for (int kw = 0; kw < 5; ++kw) {
            const float ww = wreg[kh * 5 + kw];
            #pragma unroll
            for (int j = 0; j < 8; ++j)
                acc[j] = fmaf(w[j + kw], ww, acc[j]);
        }
    }
    ushort* op = lbuf + (size_t)plane * HWn + ((row >> 3) * 7 + sx) * 64 + (row & 7) * 8;
    uint2 wa, wb;
    wa.x = cvtpk(acc[0], acc[1]); wa.y = cvtpk(acc[2], acc[3]);
    wb.x = cvtpk(acc[4], acc[5]); wb.y = cvtpk(acc[6], acc[7]);
    *(uint2*)(op)     = wa;
    *(uint2*)(op + 4) = wb;
}

// ---------------------------------------------------------------------------
// MFMA attention: r13 structure (proven 128-VGPR, no spill) with mrow
// initialized to 0 (max-free steady state: |S_log2| << 8, so the defer
// branch never fires in practice; exact rescale path kept for safety).
// ---------------------------------------------------------------------------
__global__ __launch_bounds__(256, 2)
void attention3(const ushort* __restrict__ qs, const ushort* __restrict__ ks,
                const ushort* __restrict__ vt, const int* __restrict__ idxp,
                const ushort* __restrict__ lep, ushort* __restrict__ yt)
{
    const int flat = blockIdx.x;                  // 1568 = 8*196
    const int sw = (flat & 7) * 196 + (flat >> 3);
    const int b = sw / 98;
    const int rem = sw % 98;
    const int r = rem % 49;
    const int wid = threadIdx.x >> 6, lane = threadIdx.x & 63;
    const int h = (rem / 49) * 4 + wid;
    const int col = lane & 15, g = lane >> 4;
    __shared__ ushort plds_all[4][4096];          // 8KB per wave
    ushort* pw = plds_all[wid];

    const size_t hb = ((size_t)b * NHn + h) * HWn;
    const size_t vtb = (size_t)(b * NHn + h) * 32;

    short8 qf[4];
    #pragma unroll
    for (int qt = 0; qt < 4; ++qt)
        qf[qt] = *(const short8*)(qs + (hb + (size_t)r * 64 + qt * 16 + col) * 32 + g * 8);

    f32x4 o[4][2];
    #pragma unroll
    for (int qt = 0; qt < 4; ++qt) {
        o[qt][0] = (f32x4){0.f, 0.f, 0.f, 0.f};
        o[qt][1] = (f32x4){0.f, 0.f, 0.f, 0.f};
    }
    float mrow[4] = {0.f, 0.f, 0.f, 0.f};    // max-free steady state
    float psum[4] = {0.f, 0.f, 0.f, 0.f};    // in-lane partial denominator

    const int* ip = idxp + ((size_t)b * NREGn + r) * TOPKn;
    const int4 i4 = *(const int4*)ip;
    const int idxs[4] = {i4.x, i4.y, i4.z, i4.w};

    short8 kfA[4], vfA[4];   // vf[dt*2+kc]
    {
        const int rr = idxs[0];
        #pragma unroll
        for (int kt = 0; kt < 4; ++kt)
            kfA[kt] = *(const short8*)(ks + (hb + (size_t)rr * 64 + kt * 16 + col) * 32 + g * 8);
        #pragma unroll
        for (int dt = 0; dt < 2; ++dt)
            #pragma unroll
            for (int kc = 0; kc < 2; ++kc)
                vfA[dt * 2 + kc] = *(const short8*)(vt + (vtb + dt * 16 + col) * HWn
                                                    + (size_t)rr * 64 + kc * 32 + g * 8);
    }

    #pragma unroll
    for (int t = 0; t < TOPKn; ++t) {
        short8 kfB[4], vfB[4];
        if (t < 3) {   // prefetch next region while computing this one
            const int rr = idxs[t + 1];
            #pragma unroll
            for (int kt = 0; kt < 4; ++kt)
                kfB[kt] = *(const short8*)(ks + (hb + (size_t)rr * 64 + kt * 16 + col) * 32 + g * 8);
            #pragma unroll
            for (int dt = 0; dt < 2; ++dt)
                #pragma unroll
                for (int kc = 0; kc < 2; ++kc)
                    vfB[dt * 2 + kc] = *(const short8*)(vt + (vtb + dt * 16 + col) * HWn
                                                         + (size_t)rr * 64 + kc * 32 + g * 8);
        }

        #pragma unroll
        for (int qt = 0; qt < 4; ++qt) {
            f32x4 s[4];
            #pragma unroll
            for (int kt = 0; kt < 4; ++kt)
                s[kt] = __builtin_amdgcn_mfma_f32_16x16x32_bf16(
                    kfA[kt], qf[qt], (f32x4){0.f, 0.f, 0.f, 0.f}, 0, 0, 0);

            // lane-local max (no cross-lane reduce in steady state)
            float mx = s[0][0];
            #pragma unroll
            for (int kt = 0; kt < 4; ++kt)
                #pragma unroll
                for (int e = 0; e < 4; ++e)
                    mx = fmaxf(mx, s[kt][e]);
            // defer-max: rescale only when some lane's local max grew by > 8
            if (!__all(mx - mrow[qt] <= 8.f)) {
                float mr = mx;
                mr = fmaxf(mr, __shfl_xor(mr, 16));
                mr = fmaxf(mr, __shfl_xor(mr, 32));
                const float mnew = fmaxf(mrow[qt], mr);
                const float corr = exp2f(mrow[qt] - mnew);
                mrow[qt] = mnew;
                psum[qt] *= corr;
                #pragma unroll
                for (int reg = 0; reg < 4; ++reg) {
                    const float cr = __shfl(corr, g * 4 + reg);
                    o[qt][0][reg] *= cr;
                    o[qt][1][reg] *= cr;
                }
            }
            float ls = 0.f;
            #pragma unroll
            for (int kt = 0; kt < 4; ++kt)
                #pragma unroll
                for (int e = 0; e < 4; ++e) {
                    const float p = exp2f(s[kt][e] - mrow[qt]);
                    s[kt][e] = p; ls += p;
                }
            psum[qt] += ls;
            const int qrow = qt * 16 + col;
            const int swz = (qrow & 7) << 4;
            #pragma unroll
            for (int kt = 0; kt < 4; ++kt) {
                uint2 pk;
                pk.x = cvtpk(s[kt][0], s[kt][1]);
                pk.y = cvtpk(s[kt][2], s[kt][3]);
                const int byt = (qrow * 128 + kt * 32 + g * 8) ^ swz;
                *(uint2*)((char*)pw + byt) = pk;
            }
        }

        #pragma unroll
        for (int kc = 0; kc < 2; ++kc)
            #pragma unroll
            for (int qt = 0; qt < 4; ++qt) {
                const int qrow = qt * 16 + col;
                const int byt = (qrow * 128 + kc * 64 + g * 16) ^ ((qrow & 7) << 4);
                const short8 pf = *(const short8*)((const char*)pw + byt);
                o[qt][0] = __builtin_amdgcn_mfma_f32_16x16x32_bf16(pf, vfA[0 * 2 + kc], o[qt][0], 0, 0, 0);
                o[qt][1] = __builtin_amdgcn_mfma_f32_16x16x32_bf16(pf, vfA[1 * 2 + kc], o[qt][1], 0, 0, 0);
            }

        if (t < 3) {
            #pragma unroll
            for (int i = 0; i < 4; ++i) { kfA[i] = kfB[i]; vfA[i] = vfB[i]; }
        }
    }

    // denominator: one cross-lane reduction per qt, then normalize + bounce O
    #pragma unroll
    for (int qt = 0; qt < 4; ++qt) {
        float ps = psum[qt];
        ps += __shfl_xor(ps, 16);
        ps += __shfl_xor(ps, 32);
        const float linv = 1.0f / ps;
        #pragma unroll
        for (int reg = 0; reg < 4; ++reg) {
            const float li = __shfl(linv, g * 4 + reg);
            const int row = qt * 16 + g * 4 + reg;
            const int swz = ((row >> 1) & 3) << 4;
            const uint pk = cvtpk(o[qt][0][reg] * li, o[qt][1][reg] * li);
            const int byt0 = (row * 64 + col * 2) ^ swz;
            const int byt1 = (row * 64 + (16 + col) * 2) ^ swz;
            *(ushort*)((char*)pw + byt0) = (ushort)pk;
            *(ushort*)((char*)pw + byt1) = (ushort)(pk >> 16);
        }
    }
    const ushort* lp = lep + ((size_t)b * Cn + h * 32) * HWn + (size_t)r * 64 + lane;
    ushort* yp = yt + ((size_t)b * NPn + (size_t)r * 64 + lane) * Cn + h * 32;
    const int swl = ((lane >> 1) & 3) << 4;
    #pragma unroll
    for (int c4 = 0; c4 < 8; ++c4) {
        const int byt = (lane * 64 + c4 * 8) ^ swl;
        const ushort4 ov = *(const ushort4*)((const char*)pw + byt);
        const float a0 = b2f(ov.x) + b2f(lp[(size_t)(c4 * 4 + 0) * HWn]);
        const float a1 = b2f(ov.y) + b2f(lp[(size_t)(c4 * 4 + 1) * HWn]);
        const float a2 = b2f(ov.z) + b2f(lp[(size_t)(c4 * 4 + 2) * HWn]);
        const float a3 = b2f(ov.w) + b2f(lp[(size_t)(c4 * 4 + 3) * HWn]);
        uint2 w4; w4.x = cvtpk(a0, a1); w4.y = cvtpk(a2, a3);
        *(uint2*)(yp + c4 * 4) = w4;
    }
}

// ---------------------------------------------------------------------------
extern "C" void kernel_launch(void* const* d_in, const int* in_sizes, int n_in,
                              void* d_out, int out_size, void* d_ws, size_t ws_size,
                              hipStream_t stream)
{
    const float* x      = (const float*)d_in[0];
    const float* qkv_w  = (const float*)d_in[1];
    const float* qkv_b  = (const float*)d_in[2];
    const float* lepe_w = (const float*)d_in[3];
    const float* lepe_b = (const float*)d_in[4];
    const float* out_w  = (const float*)d_in[5];
    const float* out_b  = (const float*)d_in[6];
    float* out = (float*)d_out;

    char* ws = (char*)d_ws;
    ushort* YT = (ushort*)(ws + 26214400);                       // 26,214,400
    ushort* QS = (ushort*)(ws + 52428800);                       // 25,690,112
    ushort* KS = (ushort*)(ws + 78118912);                       // 25,690,112
    ushort* VT = (ushort*)(ws + 103809024);                      // 25,690,112
    ushort* LB = (ushort*)(ws + 129499136);                      // 25,690,112
    ushort* WQ = (ushort*)(ws + 155189248);                      // 393,216
    ushort* WO = (ushort*)(ws + 155582464);                      // 131,072
    float*  XR = (float*)(ws + 155713536);                       // 802,816
    float*  QR = (float*)(ws + 156516352);                       // 802,816
    float*  KR = (float*)(ws + 157319168);                       // 802,816
    int*   IDX = (int*)(ws + 158121984);                         // 12,544

    convert_w<<<256, 256, 0, stream>>>(qkv_w, out_w, WQ, WO);
    pool_x<<<(Bn * Cn * NREGn + 255) / 256, 256, 0, stream>>>(x, XR);
    qkr_gemm<<<1568, 256, 0, stream>>>(qkv_w, qkv_b, XR, QR, KR);
    routing<<<dim3(7, 16), 256, 0, stream>>>(QR, KR, IDX);
    gemm_mfma<0><<<2400, 256, 0, stream>>>(WQ, qkv_b, nullptr, x, QS, KS, VT, nullptr);
    lepe<<<6272, 256, 0, stream>>>(VT, lepe_w, lepe_b, LB);
    attention3<<<1568, 256, 0, stream>>>(QS, KS, VT, IDX, LB, YT);
    gemm_mfma<1><<<800, 256, 0, stream>>>(WO, out_b, YT, nullptr, nullptr, nullptr, nullptr, out);
}